// Round 1
// baseline (280.970 us; speedup 1.0000x reference)
//
#include <hip/hip_runtime.h>

#define N_DIM 32
#define C_IN 64
#define C_OUT 64
#define T_DIM 288
#define V_DIM 25
#define TV 7200              // T_DIM * V_DIM
#define NTV 230400           // N_DIM * TV  (BN reduction count per channel)
#define TOTAL 14745600       // N_DIM * C_OUT * TV
#define BN_EPS 1e-5f

// ws layout (float offsets)
#define WS_WT1 0             // Wt1[c][o]  64x64  (W[:, :64] transposed)
#define WS_WT2 4096          // Wt2[c][o]  64x64  (W[:, 64:] transposed)
#define WS_SUM 8192          // gsum[64]
#define WS_SQ  8256          // gsumsq[64]

// ---------------------------------------------------------------- K0: prep
__global__ __launch_bounds__(256) void prep_kernel(const float* __restrict__ W,
                                                   float* __restrict__ ws) {
  const int tid = threadIdx.x;
  if (tid < 128) ws[WS_SUM + tid] = 0.0f;     // zero sum + sumsq
  for (int i = tid; i < 4096; i += 256) {
    const int c = i >> 6;
    const int o = i & 63;
    ws[WS_WT1 + i] = W[o * 128 + c];          // weight for fv half
    ws[WS_WT2 + i] = W[o * 128 + 64 + c];     // weight for fv_agg half
  }
}

// butterfly-transpose reduce: in v[32] per lane (destroyed); returns, on every
// lane, the sum of value index (lane&31) across the lane's 32-lane half.
__device__ __forceinline__ float reduce32_lane(float* v, int lane) {
#pragma unroll
  for (int s = 0; s < 5; ++s) {
    const int m = 1 << s;
    const bool up = (lane & m) != 0;
    const int pairs = 32 >> (s + 1);
#pragma unroll
    for (int q = 0; q < pairs; ++q) {
      const float keep = up ? v[2 * q + 1] : v[2 * q];
      const float send = up ? v[2 * q] : v[2 * q + 1];
      const float recv = __shfl_xor(send, m, 64);
      v[q] = keep + recv;
    }
  }
  return v[0];
}

// ---------------------------------------------------------------- K1: main
// one thread per output column j = (n, t, y); holds all 64 output channels.
__global__ __launch_bounds__(64) void main_kernel(const float* __restrict__ fv,
                                                  const float* __restrict__ adj,
                                                  float* __restrict__ ws,
                                                  float* __restrict__ out) {
  const int j = blockIdx.x * 64 + threadIdx.x;   // 0 .. NTV-1 (grid is exact)
  const int n = j / TV;
  const int r = j - n * TV;
  const int t = r / V_DIM;
  const int y = r - t * V_DIM;
  const int lane = threadIdx.x & 63;

  // adjacency column for this joint y (25 regs)
  float adjcol[V_DIM];
#pragma unroll
  for (int v = 0; v < V_DIM; ++v) adjcol[v] = adj[v * V_DIM + y];

  const float* __restrict__ wt1 = ws + WS_WT1;
  const float* __restrict__ wt2 = ws + WS_WT2;
  const float* base = fv + (size_t)n * (C_IN * TV) + t * V_DIM;

  float acc[C_OUT];
#pragma unroll
  for (int o = 0; o < C_OUT; ++o) acc[o] = 0.0f;

  for (int c = 0; c < C_IN; ++c) {
    const float* p = base + c * TV;
    // x  = fv[n,c,t,y];  xa = sum_v fv[n,c,t,v] * adj[v,y]
    const float x = p[y];
    float xa0 = 0.f, xa1 = 0.f, xa2 = 0.f, xa3 = 0.f;
#pragma unroll
    for (int v = 0; v < 24; v += 4) {
      xa0 = fmaf(p[v + 0], adjcol[v + 0], xa0);
      xa1 = fmaf(p[v + 1], adjcol[v + 1], xa1);
      xa2 = fmaf(p[v + 2], adjcol[v + 2], xa2);
      xa3 = fmaf(p[v + 3], adjcol[v + 3], xa3);
    }
    xa0 = fmaf(p[24], adjcol[24], xa0);
    const float xa = (xa0 + xa1) + (xa2 + xa3);

    // uniform-address weight rows (contiguous 64 floats each) -> s_load + SGPR fma
    const float* __restrict__ w1 = wt1 + c * 64;
    const float* __restrict__ w2 = wt2 + c * 64;
#pragma unroll
    for (int o = 0; o < C_OUT; ++o)
      acc[o] = fmaf(x, w1[o], fmaf(xa, w2[o], acc[o]));
  }

  // write pre-BN output (normalized in place by bn_kernel later)
  float* op = out + (size_t)n * (C_OUT * TV) + t * V_DIM + y;
#pragma unroll
  for (int o = 0; o < C_OUT; ++o) op[o * TV] = acc[o];

  // per-wave channel sums / sumsq -> global atomics
  float* gsum = ws + WS_SUM;
  float* gsq = ws + WS_SQ;

  float sq[32];
#pragma unroll
  for (int i = 0; i < 32; ++i) sq[i] = acc[i] * acc[i];
  float s0 = reduce32_lane(acc, lane);       // destroys acc[0..31]
  s0 += __shfl_xor(s0, 32, 64);
  float q0 = reduce32_lane(sq, lane);
  q0 += __shfl_xor(q0, 32, 64);

#pragma unroll
  for (int i = 0; i < 32; ++i) sq[i] = acc[32 + i] * acc[32 + i];
  float s1 = reduce32_lane(acc + 32, lane);  // destroys acc[32..63]
  s1 += __shfl_xor(s1, 32, 64);
  float q1 = reduce32_lane(sq, lane);
  q1 += __shfl_xor(q1, 32, 64);

  if (lane < 32) {
    atomicAdd(&gsum[lane], s0);
    atomicAdd(&gsum[32 + lane], s1);
    atomicAdd(&gsq[lane], q0);
    atomicAdd(&gsq[32 + lane], q1);
  }
}

// ---------------------------------------------------------------- K2: BN+ReLU
__global__ __launch_bounds__(256) void bn_kernel(const float* __restrict__ ws,
                                                 const float* __restrict__ gamma,
                                                 const float* __restrict__ beta,
                                                 float* __restrict__ out) {
  __shared__ float s_scale[C_OUT];
  __shared__ float s_shift[C_OUT];
  const int tid = threadIdx.x;
  if (tid < C_OUT) {
    const float inv = 1.0f / (float)NTV;
    const float mean = ws[WS_SUM + tid] * inv;
    const float var = fmaf(ws[WS_SQ + tid], inv, -mean * mean);
    const float sc = gamma[tid] * rsqrtf(var + BN_EPS);
    s_scale[tid] = sc;
    s_shift[tid] = fmaf(-mean, sc, beta[tid]);
  }
  __syncthreads();

  float4* o4 = reinterpret_cast<float4*>(out);
  const int total4 = TOTAL / 4;               // 3,686,400 ; TV%4==0 so o is
  const int stride = gridDim.x * blockDim.x;  // constant within each float4
  for (int i = blockIdx.x * blockDim.x + tid; i < total4; i += stride) {
    float4 v = o4[i];
    const int o = (i / 1800) & 63;            // 1800 = TV/4
    const float sc = s_scale[o];
    const float sh = s_shift[o];
    v.x = fmaxf(fmaf(v.x, sc, sh), 0.0f);
    v.y = fmaxf(fmaf(v.y, sc, sh), 0.0f);
    v.z = fmaxf(fmaf(v.z, sc, sh), 0.0f);
    v.w = fmaxf(fmaf(v.w, sc, sh), 0.0f);
    o4[i] = v;
  }
}

// ---------------------------------------------------------------- launcher
extern "C" void kernel_launch(void* const* d_in, const int* in_sizes, int n_in,
                              void* d_out, int out_size, void* d_ws, size_t ws_size,
                              hipStream_t stream) {
  const float* fv = (const float*)d_in[0];
  const float* adj = (const float*)d_in[1];
  const float* W = (const float*)d_in[2];
  // d_in[3] = b : exactly cancelled by training-mode BN mean subtraction
  const float* gamma = (const float*)d_in[4];
  const float* beta = (const float*)d_in[5];
  float* out = (float*)d_out;
  float* ws = (float*)d_ws;

  hipLaunchKernelGGL(prep_kernel, dim3(1), dim3(256), 0, stream, W, ws);
  hipLaunchKernelGGL(main_kernel, dim3(NTV / 64), dim3(64), 0, stream,
                     fv, adj, ws, out);
  hipLaunchKernelGGL(bn_kernel, dim3(2048), dim3(256), 0, stream,
                     ws, gamma, beta, out);
}